// Round 6
// baseline (122.178 us; speedup 1.0000x reference)
//
#include <hip/hip_runtime.h>

#define LEVEL 256
#define BLOCKS 8
// B=16, H=W=1024, bm=bn=128, tv = 16384/256*10 = 640

typedef float f4v __attribute__((ext_vector_type(4)));

// ---------------------------------------------------------------------------
// Kernel 1: per-image-block histogram -> clip -> cdf -> u8 map table.
// Stages pixel values as uint8 into ws so kernel 2 reads 16 MB not 64 MB.
// - img read via NON-TEMPORAL loads (read-once: don't evict the u8img lines
//   we are depositing in L2 for kernel 2; writer XCD == reader XCD since
//   k1 bid%8 = bc and k2 linear%8 = blockIdx.x = bc).
// - per-wave private histograms (4x256) kill cross-wave same-bin collisions.
// grid = 16*8*8 = 1024 blocks (= 4/CU exactly), 256 threads.
// maps8 layout in ws: uint8 maps8[16][8][8][256]  (256 KB total)
// ---------------------------------------------------------------------------
__global__ __launch_bounds__(256) void clahe_hist_kernel(const float* __restrict__ img,
                                                         unsigned char* __restrict__ maps8,
                                                         unsigned char* __restrict__ u8img) {
    __shared__ int   hist4[4][256];   // per-wave private histograms
    __shared__ float red[256];
    __shared__ float scan[256];
    __shared__ float s_me;

    const int t   = threadIdx.x;
    const int w   = t >> 6;                // wave id 0..3
    const int bid = blockIdx.x;            // 0..1023
    const int b   = bid >> 6;              // image
    const int blk = bid & 63;
    const int br  = blk >> 3;
    const int bc  = blk & 7;

#pragma unroll
    for (int q = 0; q < 4; ++q) hist4[q][t] = 0;
    __syncthreads();

    // 128x128 block = 4096 float4 loads, 16 per thread, coalesced.
    // u8 staging: 32 lanes x 4 B = 128 B per row-chunk -> full-line writes.
    const size_t base = (size_t)b * 1048576 + (size_t)(br * 128) * 1024 + (size_t)(bc * 128);
    const float* p = img + base;
    unsigned char* q8 = u8img ? (u8img + base) : nullptr;
    int* hw = hist4[w];
    for (int it = 0; it < 16; ++it) {
        int idx = it * 256 + t;            // 0..4095
        int y   = idx >> 5;                // 0..127
        int x   = (idx & 31) * 4;          // 0..124
        f4v v = __builtin_nontemporal_load((const f4v*)(p + (size_t)y * 1024 + x));
        int va = (int)v.x, vb = (int)v.y, vc = (int)v.z, vd = (int)v.w;
        atomicAdd(&hw[va], 1);
        atomicAdd(&hw[vb], 1);
        atomicAdd(&hw[vc], 1);
        atomicAdd(&hw[vd], 1);
        if (q8) {
            uchar4 pk;
            pk.x = (unsigned char)va; pk.y = (unsigned char)vb;
            pk.z = (unsigned char)vc; pk.w = (unsigned char)vd;
            *(uchar4*)(q8 + (size_t)y * 1024 + x) = pk;
        }
    }
    __syncthreads();

    // merge per-wave histograms (exact int)
    const int hsum = hist4[0][t] + hist4[1][t] + hist4[2][t] + hist4[3][t];

    // clip: tv = 640, redistribute excess uniformly (all integer-exact in fp32)
    const float tv = 640.0f;
    float h = (float)hsum;
    red[t] = fmaxf(h - tv, 0.0f);
    __syncthreads();
    for (int off = 128; off > 0; off >>= 1) {
        if (t < off) red[t] += red[t + off];
        __syncthreads();
    }
    if (t == 0) s_me = red[0] * (1.0f / 256.0f);   // exact: /2^8
    __syncthreads();
    const float me = s_me;
    float clip = floorf(((h >= tv) ? tv : h) + me);

    // inclusive scan over 256 bins (integer-valued -> exact in any order)
    scan[t] = clip;
    __syncthreads();
    for (int off = 1; off < 256; off <<= 1) {
        float add = (t >= off) ? scan[t - off] : 0.0f;
        __syncthreads();
        scan[t] += add;
        __syncthreads();
    }
    float cdf = scan[t] * (255.0f / 16384.0f);     // exact scale: 255/2^14
    int m = ((int)floorf(cdf)) & 255;
    maps8[(size_t)bid * 256 + t] = (unsigned char)m;   // exact 0..255
}

// ---------------------------------------------------------------------------
// Kernel 2: per-pixel bilinear blend of 4 neighboring block maps.
// 64x128 pixel tile per workgroup:
//   - r constant over the 64 rows; columns span two quadrants handled by
//     TWO packed LDS tables; per-thread column (and y1 factors) fixed.
//   - u8 load: uchar4, 32 lanes/row -> one full 128-B line per row-chunk;
//     with NT output stores these reads should be L2-hits from k1's writes.
//   - store: one float4/lane/iter, lanes 0-31 contiguous -> 4 full lines,
//     NON-TEMPORAL (out is never re-read; keeps u8img resident in L2).
//   - table: {lu,lb,ru,rb} packed in one u32 per bin -> random ds_read_b32
//     over all 32 banks (~2 lanes/bank, free).
// grid = (8, 16, 16) = (W/128, H/64, B), 256 threads, 8 iters x 8 rows.
// ---------------------------------------------------------------------------
template <bool U8>
__global__ __launch_bounds__(256) void clahe_map_kernel(const float* __restrict__ imgf,
                                                        const unsigned char* __restrict__ img8,
                                                        const unsigned char* __restrict__ maps8,
                                                        float* __restrict__ out) {
#pragma clang fp contract(off)
    __shared__ unsigned int mL[256];   // packed {lu,lb,ru,rb} for left  64 cols
    __shared__ unsigned int mR[256];   // packed {lu,lb,ru,rb} for right 64 cols

    const int t  = threadIdx.x;
    const int b  = blockIdx.z;
    const int i0 = blockIdx.y * 64;
    const int j0 = blockIdx.x * 128;

    // r = trunc((i-64)/128) toward zero, constant over the 64-row tile
    const int r  = (i0 >= 64) ? ((i0 - 64) >> 7) : 0;
    const int rp = min(r + 1, BLOCKS - 1);
    const bool rEdge = (r >= BLOCKS - 1);

    // column quadrants: left half [j0, j0+64), right half [j0+64, j0+128)
    const int cL  = (j0 >= 64) ? ((j0 - 64) >> 7) : 0;
    const int cR  = j0 >> 7;
    const int cLp = min(cL + 1, BLOCKS - 1);
    const int cRp = min(cR + 1, BLOCKS - 1);

    const unsigned char* mb = maps8 + (size_t)b * 64 * 256;
    {
        unsigned lu = mb[(r  * 8 + cL ) * 256 + t];
        unsigned lb = mb[(rp * 8 + cL ) * 256 + t];
        unsigned ru = mb[(r  * 8 + cLp) * 256 + t];
        unsigned rb = mb[(rp * 8 + cLp) * 256 + t];
        mL[t] = lu | (lb << 8) | (ru << 16) | (rb << 24);
        unsigned lu2 = mb[(r  * 8 + cR ) * 256 + t];
        unsigned lb2 = mb[(rp * 8 + cR ) * 256 + t];
        unsigned ru2 = mb[(r  * 8 + cRp) * 256 + t];
        unsigned rb2 = mb[(rp * 8 + cRp) * 256 + t];
        mR[t] = lu2 | (lb2 << 8) | (ru2 << 16) | (rb2 << 24);
    }
    __syncthreads();

    // per-thread fixed column: j = (t&31)*4 in [0,124]
    const int jc   = (t & 31) * 4;
    const int half = jc >> 6;                 // 0 = left quadrant, 1 = right
    const unsigned int* mt = half ? mR : mL;
    const int cq   = half ? cR : cL;
    const bool cEdge = (cq >= BLOCKS - 1);
    const float cbase = (float)(cq * 128 + 64);

    float y1v[4], y0v[4];
#pragma unroll
    for (int k = 0; k < 4; ++k) {
        y1v[k] = cEdge ? 0.0f : ((float)(j0 + jc + k) - cbase) * 0.0078125f;
        y0v[k] = 1.0f - y1v[k];
    }

    const size_t ibase = (size_t)b * 1048576;
    const float rbase = (float)(r * 128 + 64);
    const int row0 = t >> 5;                  // 0..7

#pragma unroll
    for (int it = 0; it < 8; ++it) {
        const int i = i0 + it * 8 + row0;
        const size_t off = ibase + (size_t)i * 1024 + j0 + jc;

        int vv[4];
        if (U8) {
            uchar4 px = *(const uchar4*)(img8 + off);
            vv[0] = px.x; vv[1] = px.y; vv[2] = px.z; vv[3] = px.w;
        } else {
            float4 px = *(const float4*)(imgf + off);
            vv[0] = (int)px.x; vv[1] = (int)px.y; vv[2] = (int)px.z; vv[3] = (int)px.w;
        }

        const float x1 = rEdge ? 0.0f : ((float)i - rbase) * 0.0078125f;
        const float x0 = 1.0f - x1;

        f4v o4;
#pragma unroll
        for (int k = 0; k < 4; ++k) {
            const unsigned mm = mt[vv[k]];
            // exact integers 0..255 -> v_cvt_f32_ubyte{0..3}
            const float lu = (float)(mm & 255u);
            const float lb = (float)((mm >> 8) & 255u);
            const float ru = (float)((mm >> 16) & 255u);
            const float rb = (float)(mm >> 24);
            // exact expression order of the reference; no FMA contraction
            float o = y0v[k] * (x0 * lu + x1 * lb) + y1v[k] * (x0 * ru + x1 * rb);
            // trunc toward zero then floor-mod 256 (two's-complement & 255)
            o4[k] = (float)(((int)o) & 255);
        }
        __builtin_nontemporal_store(o4, (f4v*)(out + off));
    }
}

extern "C" void kernel_launch(void* const* d_in, const int* in_sizes, int n_in,
                              void* d_out, int out_size, void* d_ws, size_t ws_size,
                              hipStream_t stream) {
    const float* img = (const float*)d_in[0];
    float* out = (float*)d_out;

    unsigned char* maps8 = (unsigned char*)d_ws;            // 256 KB
    const size_t maps_bytes = (size_t)1024 * 256;           // 16*64*256 u8
    const size_t u8_bytes   = (size_t)16 * 1024 * 1024;
    const bool use_u8 = ws_size >= maps_bytes + u8_bytes;
    unsigned char* u8img = use_u8 ? ((unsigned char*)d_ws + maps_bytes) : nullptr;

    clahe_hist_kernel<<<dim3(1024), dim3(256), 0, stream>>>(img, maps8, u8img);
    if (use_u8) {
        clahe_map_kernel<true><<<dim3(8, 16, 16), dim3(256), 0, stream>>>(
            nullptr, u8img, maps8, out);
    } else {
        clahe_map_kernel<false><<<dim3(8, 16, 16), dim3(256), 0, stream>>>(
            img, nullptr, maps8, out);
    }
}

// Round 7
// 120.885 us; speedup vs baseline: 1.0107x; 1.0107x over previous
//
#include <hip/hip_runtime.h>

#define LEVEL 256
#define BLOCKS 8
// B=16, H=W=1024, bm=bn=128, tv = 16384/256*10 = 640

// ---------------------------------------------------------------------------
// Kernel 1: per-image-block histogram -> clip -> cdf -> u8 map table.
// Also stages the pixel values as uint8 into ws so kernel 2 reads 16 MB
// instead of 64 MB. (Identical to the proven 124-us round-0 kernel except
// maps are stored as exact u8 instead of float.)
// grid = 16*8*8 = 1024 blocks, 256 threads each.
// maps8 layout in ws: uint8 maps8[16][8][8][256]  (256 KB total)
//
// PROVEN 118.5 us (round 5). Round-6 variants (NT loads/stores, per-wave
// private histograms) regressed to 122.2 -> reverted.
// ---------------------------------------------------------------------------
__global__ __launch_bounds__(256) void clahe_hist_kernel(const float* __restrict__ img,
                                                         unsigned char* __restrict__ maps8,
                                                         unsigned char* __restrict__ u8img) {
    __shared__ int   hist[256];
    __shared__ float red[256];
    __shared__ float scan[256];
    __shared__ float s_me;

    const int t   = threadIdx.x;
    const int bid = blockIdx.x;            // 0..1023
    const int b   = bid >> 6;              // image
    const int blk = bid & 63;
    const int br  = blk >> 3;
    const int bc  = blk & 7;

    hist[t] = 0;
    __syncthreads();

    // 128x128 block = 4096 float4 loads, 16 per thread, coalesced.
    // u8 staging: 32 lanes x 4 B = 128 B per row-chunk -> full-line writes.
    const size_t base = (size_t)b * 1048576 + (size_t)(br * 128) * 1024 + (size_t)(bc * 128);
    const float* p = img + base;
    unsigned char* q8 = u8img ? (u8img + base) : nullptr;
    for (int it = 0; it < 16; ++it) {
        int idx = it * 256 + t;            // 0..4095
        int y   = idx >> 5;                // 0..127
        int x   = (idx & 31) * 4;          // 0..124
        float4 v = *(const float4*)(p + (size_t)y * 1024 + x);
        int va = (int)v.x, vb = (int)v.y, vc = (int)v.z, vd = (int)v.w;
        atomicAdd(&hist[va], 1);
        atomicAdd(&hist[vb], 1);
        atomicAdd(&hist[vc], 1);
        atomicAdd(&hist[vd], 1);
        if (q8) {
            uchar4 pk;
            pk.x = (unsigned char)va; pk.y = (unsigned char)vb;
            pk.z = (unsigned char)vc; pk.w = (unsigned char)vd;
            *(uchar4*)(q8 + (size_t)y * 1024 + x) = pk;
        }
    }
    __syncthreads();

    // clip: tv = 640, redistribute excess uniformly (all integer-exact in fp32)
    const float tv = 640.0f;
    float h = (float)hist[t];
    red[t] = fmaxf(h - tv, 0.0f);
    __syncthreads();
    for (int off = 128; off > 0; off >>= 1) {
        if (t < off) red[t] += red[t + off];
        __syncthreads();
    }
    if (t == 0) s_me = red[0] * (1.0f / 256.0f);   // exact: /2^8
    __syncthreads();
    const float me = s_me;
    float clip = floorf(((h >= tv) ? tv : h) + me);

    // inclusive scan over 256 bins (integer-valued -> exact in any order)
    scan[t] = clip;
    __syncthreads();
    for (int off = 1; off < 256; off <<= 1) {
        float add = (t >= off) ? scan[t - off] : 0.0f;
        __syncthreads();
        scan[t] += add;
        __syncthreads();
    }
    float cdf = scan[t] * (255.0f / 16384.0f);     // exact scale: 255/2^14
    int m = ((int)floorf(cdf)) & 255;
    maps8[(size_t)bid * 256 + t] = (unsigned char)m;   // exact 0..255
}

// ---------------------------------------------------------------------------
// Kernel 2: per-pixel bilinear blend of 4 neighboring block maps.
// 64x128 pixel tile per workgroup:
//   - r constant over the 64 rows (boundaries at i = 64 + 128*m);
//   - columns span two quadrants (left 64 / right 64), handled by TWO
//     packed LDS tables; each thread's column (hence quadrant and y1
//     factors) is FIXED across all row iterations.
//   - u8 load: uchar4, 32 lanes/row -> one full 128-B line per row-chunk.
//   - store: one float4/lane/iter, lanes 0-31 contiguous -> 4 full lines.
//   - table: {lu,lb,ru,rb} packed as 4 bytes in one u32 per bin -> random
//     lookup is ds_read_b32 spread over all 32 banks (~2 lanes/bank, free)
//     instead of float4 ds_read_b128 crowding 8 bank groups.
// grid = (8, 16, 16) = (W/128, H/64, B), 256 threads, 8 iters x 8 rows.
// ---------------------------------------------------------------------------
template <bool U8>
__global__ __launch_bounds__(256) void clahe_map_kernel(const float* __restrict__ imgf,
                                                        const unsigned char* __restrict__ img8,
                                                        const unsigned char* __restrict__ maps8,
                                                        float* __restrict__ out) {
#pragma clang fp contract(off)
    __shared__ unsigned int mL[256];   // packed {lu,lb,ru,rb} for left  64 cols
    __shared__ unsigned int mR[256];   // packed {lu,lb,ru,rb} for right 64 cols

    const int t  = threadIdx.x;
    const int b  = blockIdx.z;
    const int i0 = blockIdx.y * 64;
    const int j0 = blockIdx.x * 128;

    // r = trunc((i-64)/128) toward zero, constant over the 64-row tile
    const int r  = (i0 >= 64) ? ((i0 - 64) >> 7) : 0;
    const int rp = min(r + 1, BLOCKS - 1);
    const bool rEdge = (r >= BLOCKS - 1);

    // column quadrants: left half [j0, j0+64), right half [j0+64, j0+128)
    const int cL  = (j0 >= 64) ? ((j0 - 64) >> 7) : 0;
    const int cR  = j0 >> 7;
    const int cLp = min(cL + 1, BLOCKS - 1);
    const int cRp = min(cR + 1, BLOCKS - 1);

    const unsigned char* mb = maps8 + (size_t)b * 64 * 256;
    {
        unsigned lu = mb[(r  * 8 + cL ) * 256 + t];
        unsigned lb = mb[(rp * 8 + cL ) * 256 + t];
        unsigned ru = mb[(r  * 8 + cLp) * 256 + t];
        unsigned rb = mb[(rp * 8 + cLp) * 256 + t];
        mL[t] = lu | (lb << 8) | (ru << 16) | (rb << 24);
        unsigned lu2 = mb[(r  * 8 + cR ) * 256 + t];
        unsigned lb2 = mb[(rp * 8 + cR ) * 256 + t];
        unsigned ru2 = mb[(r  * 8 + cRp) * 256 + t];
        unsigned rb2 = mb[(rp * 8 + cRp) * 256 + t];
        mR[t] = lu2 | (lb2 << 8) | (ru2 << 16) | (rb2 << 24);
    }
    __syncthreads();

    // per-thread fixed column: j = (t&31)*4 in [0,124]
    const int jc   = (t & 31) * 4;
    const int half = jc >> 6;                 // 0 = left quadrant, 1 = right
    const unsigned int* mt = half ? mR : mL;
    const int cq   = half ? cR : cL;
    const bool cEdge = (cq >= BLOCKS - 1);
    const float cbase = (float)(cq * 128 + 64);

    float y1v[4], y0v[4];
#pragma unroll
    for (int k = 0; k < 4; ++k) {
        y1v[k] = cEdge ? 0.0f : ((float)(j0 + jc + k) - cbase) * 0.0078125f;
        y0v[k] = 1.0f - y1v[k];
    }

    const size_t ibase = (size_t)b * 1048576;
    const float rbase = (float)(r * 128 + 64);
    const int row0 = t >> 5;                  // 0..7

#pragma unroll
    for (int it = 0; it < 8; ++it) {
        const int i = i0 + it * 8 + row0;
        const size_t off = ibase + (size_t)i * 1024 + j0 + jc;

        int vv[4];
        if (U8) {
            uchar4 px = *(const uchar4*)(img8 + off);
            vv[0] = px.x; vv[1] = px.y; vv[2] = px.z; vv[3] = px.w;
        } else {
            float4 px = *(const float4*)(imgf + off);
            vv[0] = (int)px.x; vv[1] = (int)px.y; vv[2] = (int)px.z; vv[3] = (int)px.w;
        }

        const float x1 = rEdge ? 0.0f : ((float)i - rbase) * 0.0078125f;
        const float x0 = 1.0f - x1;

        float4 o4;
        float* ov = (float*)&o4;
#pragma unroll
        for (int k = 0; k < 4; ++k) {
            const unsigned mm = mt[vv[k]];
            // exact integers 0..255 -> v_cvt_f32_ubyte{0..3}
            const float lu = (float)(mm & 255u);
            const float lb = (float)((mm >> 8) & 255u);
            const float ru = (float)((mm >> 16) & 255u);
            const float rb = (float)(mm >> 24);
            // exact expression order of the reference; no FMA contraction
            float o = y0v[k] * (x0 * lu + x1 * lb) + y1v[k] * (x0 * ru + x1 * rb);
            // trunc toward zero then floor-mod 256 (two's-complement & 255)
            ov[k] = (float)(((int)o) & 255);
        }
        *(float4*)(out + off) = o4;
    }
}

extern "C" void kernel_launch(void* const* d_in, const int* in_sizes, int n_in,
                              void* d_out, int out_size, void* d_ws, size_t ws_size,
                              hipStream_t stream) {
    const float* img = (const float*)d_in[0];
    float* out = (float*)d_out;

    unsigned char* maps8 = (unsigned char*)d_ws;            // 256 KB
    const size_t maps_bytes = (size_t)1024 * 256;           // 16*64*256 u8
    const size_t u8_bytes   = (size_t)16 * 1024 * 1024;
    const bool use_u8 = ws_size >= maps_bytes + u8_bytes;
    unsigned char* u8img = use_u8 ? ((unsigned char*)d_ws + maps_bytes) : nullptr;

    clahe_hist_kernel<<<dim3(1024), dim3(256), 0, stream>>>(img, maps8, u8img);
    if (use_u8) {
        clahe_map_kernel<true><<<dim3(8, 16, 16), dim3(256), 0, stream>>>(
            nullptr, u8img, maps8, out);
    } else {
        clahe_map_kernel<false><<<dim3(8, 16, 16), dim3(256), 0, stream>>>(
            img, nullptr, maps8, out);
    }
}